// Round 14
// baseline (236.336 us; speedup 1.0000x reference)
//
#include <hip/hip_runtime.h>
#include <hip/hip_bf16.h>
#include <stdint.h>

typedef __attribute__((ext_vector_type(4))) float f32x4;
typedef __attribute__((ext_vector_type(8))) short bf16x8;

#define BK 64

__device__ inline void gload_lds16(const void* g, void* l) {
    __builtin_amdgcn_global_load_lds(
        (const __attribute__((address_space(1))) void*)g,
        (__attribute__((address_space(3))) void*)l, 16, 0, 0);
}

__device__ inline void wg_barrier() {
    asm volatile("s_barrier" ::: "memory");
}
#define SCHED0 __builtin_amdgcn_sched_barrier(0)
#define VMW(n) asm volatile("s_waitcnt vmcnt(" #n ")" ::: "memory")
#define LGKM0  asm volatile("s_waitcnt lgkmcnt(0)" ::: "memory")

// bijective XCD swizzle (m204)
__device__ inline int xcd_swizzle(int orig, int nwg) {
    int q = nwg >> 3, r = nwg & 7;
    int xcd = orig & 7, idx = orig >> 3;
    int base = (xcd < r) ? xcd * (q + 1) : r * (q + 1) + (xcd - r) * q;
    return base + idx;
}

__device__ inline float b2f(short s) {
    union { float f; unsigned u; } x; x.u = ((unsigned)(unsigned short)s) << 16; return x.f;
}
__device__ inline short f2bs(float f) {
    __hip_bfloat16 h = __float2bfloat16(f);
    short s; __builtin_memcpy(&s, &h, 2); return s;
}

// Fused pre-pass (R9 shape): features one-shot, weights after.
__device__ inline void wt_tile(const float* __restrict__ W, __hip_bfloat16* __restrict__ WT,
                               int K, int N, int KP, int tid, int bid) {
    __shared__ float tile[32][33];
    const int ntn = N >> 5;
    const int tk = bid / ntn, tn = bid - tk * ntn;
    const int k0 = tk * 32, n0 = tn * 32;
    const int c = tid & 31, r8 = tid >> 5;
    #pragma unroll
    for (int p = 0; p < 4; p++) {
        int k = k0 + r8 + p * 8;
        tile[r8 + p * 8][c] = (k < K) ? W[(size_t)k * N + n0 + c] : 0.f;
    }
    __syncthreads();
    #pragma unroll
    for (int p = 0; p < 4; p++) {
        int n = n0 + r8 + p * 8;
        WT[(size_t)n * KP + k0 + c] = __float2bfloat16(tile[c][r8 + p * 8]);
    }
}

__global__ __launch_bounds__(256)
void prepass(const float* __restrict__ feat, __hip_bfloat16* __restrict__ featbf,
             const float* __restrict__ We, __hip_bfloat16* __restrict__ WeTt,
             __hip_bfloat16* __restrict__ WeTb,
             const float* __restrict__ W1a, __hip_bfloat16* __restrict__ W1aT,
             const float* __restrict__ W1b, __hip_bfloat16* __restrict__ W1bT,
             const float* __restrict__ W2a, __hip_bfloat16* __restrict__ W2aT,
             const float* __restrict__ W2b, __hip_bfloat16* __restrict__ W2bT)
{
    const int bid = blockIdx.x;
    const int tid = threadIdx.x;
    if (bid < 17408) {
        int i = bid * 256 + tid;
        int r = i / 272, c8 = (i % 272) * 8;
        __hip_bfloat16 tmp[8];
        if (c8 < 2144) {
            const float4* p = (const float4*)(feat + (size_t)r * 2144 + c8);
            float4 x0 = p[0], x1 = p[1];
            tmp[0] = __float2bfloat16(x0.x); tmp[1] = __float2bfloat16(x0.y);
            tmp[2] = __float2bfloat16(x0.z); tmp[3] = __float2bfloat16(x0.w);
            tmp[4] = __float2bfloat16(x1.x); tmp[5] = __float2bfloat16(x1.y);
            tmp[6] = __float2bfloat16(x1.z); tmp[7] = __float2bfloat16(x1.w);
        } else {
            #pragma unroll
            for (int j = 0; j < 8; j++) tmp[j] = __float2bfloat16(0.f);
        }
        *(bf16x8*)&featbf[(size_t)r * 2176 + c8] = *(const bf16x8*)tmp;
        return;
    }
    int b = bid - 17408;
    if      (b < 2176) wt_tile(We,                WeTt, 2144, 1024, 2176, tid, b);
    else if (b < 4352) wt_tile(We + 2144 * 1024,  WeTb, 2144, 1024, 2176, tid, b - 2176);
    else if (b < 5376) wt_tile(W1a, W1aT, 1024, 1024, 1024, tid, b - 4352);
    else if (b < 5888) wt_tile(W1b, W1bT, 1024,  512, 1024, tid, b - 5376);
    else if (b < 6144) wt_tile(W2a, W2aT,  512,  512,  512, tid, b - 5888);
    else               wt_tile(W2b, W2bT,  512,  512,  512, tid, b - 6144);
}

// Phase-split GEMM, m201 skeleton: per phase {reads+stage -> barrier ->
// lgkmcnt(0) -> sched_barrier -> setprio MFMA -> barrier}. Counted vmcnt,
// never drains mid-loop. T2 swizzle. 256 x BN_ tile, 8 waves (2Mx4N).
// NF=4 ledger (2 loads/stage-unit; per-tile order ph0:B01(t+1) ph1:B23(t+1)
//   ph2:A02(t+2) ph3:A13(t+2)): gate at ph3(t) for tile t+1 = VMW(4)
//   (outstanding 12 -> retires A(t+1),B(t+1)); kt==ke-2 -> VMW(0).
// NF=2 ledger (ph0:A13(t+1), ph1:A02,B01(t+2)): ph1-entry gate VMW(6)
//   (retires A13(t)); ph1-exit gate VMW(6) (retires A02,B01(t+1));
//   last tiles: VMW(0)/VMW(2).
// RES_MODE: 0 none, 1 bf16 res[M][N], 2 f32 res[row>>5][N]
// OUTK: 0 f32 scalar (split-K partials), 1 bf16 leaky, 2 bf16 raw, 3 both
template<int BN_, int RES_MODE, int OUTK>
__global__ __launch_bounds__(512, 2)
void gemmk(const __hip_bfloat16* __restrict__ A, int lda,
           const __hip_bfloat16* __restrict__ Bt,
           const float* __restrict__ bias,
           const __hip_bfloat16* __restrict__ resb,
           const float* __restrict__ resf,
           __hip_bfloat16* __restrict__ outb,
           __hip_bfloat16* __restrict__ outb2,
           float* __restrict__ outf,
           int M, int N, int K, int gx)
{
    constexpr int NF  = BN_ / 64;           // 4 or 2
    constexpr int REL = NF * 16;            // per-wave col span
    __shared__ __hip_bfloat16 lds[2][(256 + BN_) * BK];

    const int nwg  = gridDim.x;
    const int wgid = xcd_swizzle(blockIdx.x, nwg);
    const int by   = wgid / gx;
    const int bx   = wgid - by * gx;

    const int t    = threadIdx.x;
    const int lane = t & 63;
    const int wv   = t >> 6;
    const int wr   = wv >> 2;               // 0..1 (128-row half)
    const int wc   = wv & 3;                // 0..3 (REL-wide col strip)

    const int row0 = by * 256;
    const int col0 = bx * BN_;

    const int NT = K / BK;
    const int split = blockIdx.y;
    const int kb = (split * NT) / gridDim.y;
    const int ke = ((split + 1) * NT) / gridDim.y;
    float* outfs = outf;
    if (OUTK == 0 && gridDim.y > 1) outfs = outf + (size_t)split * M * N;

    const int srow = t >> 3;                                 // 0..63
    const int sc8  = (t & 7) * 8;
    const int scol = sc8 ^ ((srow & 7) << 3);                // inverse-swz src col
    const int sdst = sc8;                                    // linear LDS dest

    f32x4 acc[8][NF];
    #pragma unroll
    for (int i = 0; i < 8; i++)
        #pragma unroll
        for (int j = 0; j < NF; j++)
            acc[i][j] = f32x4{0.f, 0.f, 0.f, 0.f};

    const int lrow = lane & 15;
    const int lk   = (lane >> 4) * 8;
    const int rxor = (lrow & 7) << 3;

    auto stA = [&](int buf, int k0, int b) {
        gload_lds16(A + (size_t)(row0 + b * 64 + srow) * lda + k0 + scol,
                    &lds[buf][(b * 64 + srow) * BK + sdst]);
    };
    auto stB = [&](int buf, int k0, int b) {
        gload_lds16(Bt + (size_t)(col0 + b * 64 + srow) * K + k0 + scol,
                    &lds[buf][(256 + b * 64 + srow) * BK + sdst]);
    };

    bf16x8 af[4][2];
    auto rdA = [&](int buf, int ih) {       // ih=0: bands {0,2}; ih=1: {1,3}
        #pragma unroll
        for (int i = 0; i < 4; ++i)
            #pragma unroll
            for (int h = 0; h < 2; ++h)
                af[i][h] = *(const bf16x8*)
                    &lds[buf][(wr * 128 + (ih * 4 + i) * 16 + lrow) * BK + ((h * 32 + lk) ^ rxor)];
    };
    bf16x8 bgl[2][2], bgh[2][2];
    auto rdB2 = [&](int buf, int jb, bf16x8 (&bg)[2][2]) {
        #pragma unroll
        for (int j = 0; j < 2; ++j)
            #pragma unroll
            for (int h = 0; h < 2; ++h)
                bg[j][h] = *(const bf16x8*)
                    &lds[buf][(256 + wc * REL + (jb + j) * 16 + lrow) * BK + ((h * 32 + lk) ^ rxor)];
    };

#define MFMA_Q(BG, IB, JB)                                                    \
    do {                                                                      \
        __builtin_amdgcn_s_setprio(1);                                        \
        _Pragma("unroll") for (int h_ = 0; h_ < 2; ++h_)                      \
        _Pragma("unroll") for (int i_ = 0; i_ < 4; ++i_)                      \
        _Pragma("unroll") for (int j_ = 0; j_ < 2; ++j_)                      \
            acc[(IB) + i_][(JB) + j_] = __builtin_amdgcn_mfma_f32_16x16x32_bf16( \
                af[i_][h_], BG[j_][h_], acc[(IB) + i_][(JB) + j_], 0, 0, 0);  \
        __builtin_amdgcn_s_setprio(0);                                        \
    } while (0)

    // ---- prologue (issue order defines the vmcnt ledger!) ----
    {
        const int k0 = kb * BK, k1 = (kb + 1) * BK;
        if constexpr (NF == 4) {
            stA(0, k0, 0); stA(0, k0, 2); stA(0, k0, 1); stA(0, k0, 3);
            stB(0, k0, 0); stB(0, k0, 1); stB(0, k0, 2); stB(0, k0, 3);
            stA(1, k1, 0); stA(1, k1, 2); stA(1, k1, 1); stA(1, k1, 3);
            VMW(4);                         // A(0),B(0) landed; A(1) in flight
        } else {
            stA(0, k0, 0); stA(0, k0, 2); stB(0, k0, 0); stB(0, k0, 1);
            stA(0, k0, 1); stA(0, k0, 3);
            stA(1, k1, 0); stA(1, k1, 2); stB(1, k1, 0); stB(1, k1, 1);
            VMW(6);                         // A02(0),B01(0) landed (oldest 4)
        }
        wg_barrier();
    }

    int cur = 0;
    for (int kt = kb; kt < ke; ++kt) {
        const bool pf1 = (kt + 1 < ke), pf2 = (kt + 2 < ke);
        const int nk1 = (kt + 1) * BK, nk2 = (kt + 2) * BK;
        const int nxt = cur ^ 1;
        if constexpr (NF == 4) {
            // ph0: reads afA + bgl; stage B01(t+1)
            rdA(cur, 0); rdB2(cur, 0, bgl);
            if (pf1) { stB(nxt, nk1, 0); stB(nxt, nk1, 1); }
            wg_barrier(); LGKM0; SCHED0;
            MFMA_Q(bgl, 0, 0);
            wg_barrier();
            // ph1: reads bgh; stage B23(t+1)
            rdB2(cur, 2, bgh);
            if (pf1) { stB(nxt, nk1, 2); stB(nxt, nk1, 3); }
            wg_barrier(); LGKM0; SCHED0;
            MFMA_Q(bgh, 0, 2);
            wg_barrier();
            // ph2: reads afB; stage A02(t+2) into cur (bands 0,2 dead since ph0)
            rdA(cur, 1);
            if (pf2) { stA(cur, nk2, 0); stA(cur, nk2, 2); }
            wg_barrier(); LGKM0; SCHED0;
            MFMA_Q(bgl, 4, 0);
            wg_barrier();
            // ph3: stage A13(t+2); gate tile t+1 (outstanding 12 -> VMW(4)
            // retires A(t+1),B(t+1))
            if (pf2) { stA(cur, nk2, 1); stA(cur, nk2, 3); }
            if (pf1) { if (kt == ke - 2) VMW(0); else VMW(4); }
            wg_barrier(); SCHED0;
            MFMA_Q(bgh, 4, 2);
            wg_barrier();
        } else {
            // ph0: reads afA + bgl; stage A13(t+1)
            rdA(cur, 0); rdB2(cur, 0, bgl);
            if (pf1) { stA(nxt, nk1, 1); stA(nxt, nk1, 3); }
            wg_barrier(); LGKM0; SCHED0;
            MFMA_Q(bgl, 0, 0);
            wg_barrier();
            // ph1: entry gate (A13(t) landed), reads afB; stage A02,B01(t+2);
            // exit gate (A02,B01(t+1) landed)
            if (kt == ke - 1) VMW(0); else VMW(6);
            rdA(cur, 1);
            if (pf2) { stA(cur, nk2, 0); stA(cur, nk2, 2); stB(cur, nk2, 0); stB(cur, nk2, 1); }
            if (kt == ke - 2) { VMW(2); } else if (pf2) { VMW(6); }
            wg_barrier(); LGKM0; SCHED0;
            MFMA_Q(bgl, 4, 0);
            wg_barrier();
        }
        cur ^= 1;
    }
#undef MFMA_Q

    // ---- epilogue ----
    if constexpr (OUTK == 0) {
        #pragma unroll
        for (int j = 0; j < NF; j++) {
            const int col = col0 + wc * REL + j * 16 + lrow;
            #pragma unroll
            for (int i = 0; i < 8; i++) {
                const int rbase = row0 + wr * 128 + i * 16 + (lane >> 4) * 4;
                #pragma unroll
                for (int r = 0; r < 4; r++)
                    outfs[(size_t)(rbase + r) * N + col] = acc[i][j][r];
            }
        }
    } else {
        wg_barrier();                       // all LDS reads/loads retired
        __hip_bfloat16* eb = &lds[0][0] + wv * (128 * REL);
        #pragma unroll
        for (int i = 0; i < 8; i++)
            #pragma unroll
            for (int j = 0; j < NF; j++)
                #pragma unroll
                for (int r = 0; r < 4; r++)
                    eb[(i * 16 + (lane >> 4) * 4 + r) * REL + j * 16 + lrow] =
                        __float2bfloat16(acc[i][j][r]);
        constexpr int LPR = REL / 8;
        constexpr int RPI = 64 / LPR;
        constexpr int NIT = 128 / RPI;
        const int lrr = lane / LPR;
        const int lcc = (lane % LPR) * 8;
        const int col = col0 + wc * REL + lcc;
        float bvv[8];
        if (bias) {
            float4 b0 = *(const float4*)&bias[col];
            float4 b1 = *(const float4*)&bias[col + 4];
            bvv[0] = b0.x; bvv[1] = b0.y; bvv[2] = b0.z; bvv[3] = b0.w;
            bvv[4] = b1.x; bvv[5] = b1.y; bvv[6] = b1.z; bvv[7] = b1.w;
        } else {
            #pragma unroll
            for (int e = 0; e < 8; e++) bvv[e] = 0.f;
        }
        #pragma unroll
        for (int it = 0; it < NIT; it++) {
            const int rl  = it * RPI + lrr;
            const int row = row0 + wr * 128 + rl;
            bf16x8 v8 = *(bf16x8*)&eb[rl * REL + lcc];
            float vv[8];
            #pragma unroll
            for (int e = 0; e < 8; e++) vv[e] = b2f(v8[e]) + bvv[e];
            if constexpr (RES_MODE == 1) {
                bf16x8 r8 = *(const bf16x8*)&resb[(size_t)row * N + col];
                #pragma unroll
                for (int e = 0; e < 8; e++) vv[e] += b2f(r8[e]);
            }
            if constexpr (RES_MODE == 2) {
                const float* rp = &resf[(size_t)(row >> 5) * N + col];
                float4 r0 = *(const float4*)rp;
                float4 r1 = *(const float4*)(rp + 4);
                vv[0] += r0.x; vv[1] += r0.y; vv[2] += r0.z; vv[3] += r0.w;
                vv[4] += r1.x; vv[5] += r1.y; vv[6] += r1.z; vv[7] += r1.w;
            }
            bf16x8 o1, o2;
            #pragma unroll
            for (int e = 0; e < 8; e++) {
                float lv = vv[e] >= 0.f ? vv[e] : 0.01f * vv[e];
                if constexpr (OUTK == 1) o1[e] = f2bs(lv);
                if constexpr (OUTK == 2) o1[e] = f2bs(vv[e]);
                if constexpr (OUTK == 3) { o1[e] = f2bs(lv); o2[e] = f2bs(vv[e]); }
            }
            *(bf16x8*)&outb[(size_t)row * N + col] = o1;
            if constexpr (OUTK == 3)
                *(bf16x8*)&outb2[(size_t)row * N + col] = o2;
        }
    }
}

// eanchor = sum of 8 split-K partials + be
__global__ __launch_bounds__(256)
void anchor_reduce(const float* __restrict__ part, const float* __restrict__ be,
                   float* __restrict__ out) {
    int i = blockIdx.x * 256 + threadIdx.x;
    if (i >= 512 * 1024) return;
    const int S = 512 * 1024;
    int col = i & 1023;
    float s = be[col];
    #pragma unroll
    for (int p = 0; p < 8; p++) s += part[i + p * S];
    out[i] = s;
}

// out[row] = leaky(h[row]) @ Wd + bd + [0,0,1], h bf16
__global__ __launch_bounds__(256)
void final_head(const __hip_bfloat16* __restrict__ h, const float* __restrict__ Wd,
                const float* __restrict__ bd, float* __restrict__ out)
{
    int row  = blockIdx.x * 4 + (threadIdx.x >> 6);
    int lane = threadIdx.x & 63;
    const __hip_bfloat16* hr = h + (size_t)row * 512;
    bf16x8 v8 = *(const bf16x8*)&hr[lane * 8];
    float s0 = 0.f, s1 = 0.f, s2 = 0.f;
    #pragma unroll
    for (int e = 0; e < 8; e++) {
        float v = b2f(v8[e]);
        v = v >= 0.f ? v : 0.01f * v;
        int k = lane * 8 + e;
        s0 += v * Wd[k * 3 + 0];
        s1 += v * Wd[k * 3 + 1];
        s2 += v * Wd[k * 3 + 2];
    }
    #pragma unroll
    for (int off = 32; off > 0; off >>= 1) {
        s0 += __shfl_down(s0, off);
        s1 += __shfl_down(s1, off);
        s2 += __shfl_down(s2, off);
    }
    if (lane == 0) {
        out[row * 3 + 0] = s0 + bd[0];
        out[row * 3 + 1] = s1 + bd[1];
        out[row * 3 + 2] = s2 + bd[2] + 1.0f;
    }
}

extern "C" void kernel_launch(void* const* d_in, const int* in_sizes, int n_in,
                              void* d_out, int out_size, void* d_ws, size_t ws_size,
                              hipStream_t stream)
{
    const float* features = (const float*)d_in[0];
    const float* We  = (const float*)d_in[1];
    const float* be  = (const float*)d_in[2];
    const float* W1a = (const float*)d_in[3];
    const float* b1a = (const float*)d_in[4];
    const float* W1b = (const float*)d_in[5];
    const float* b1b = (const float*)d_in[6];
    const float* W2a = (const float*)d_in[7];
    const float* b2a = (const float*)d_in[8];
    const float* W2b = (const float*)d_in[9];
    const float* b2b = (const float*)d_in[10];
    const float* Wd  = (const float*)d_in[11];
    const float* bd  = (const float*)d_in[12];
    float* out = (float*)d_out;

    char* ws = (char*)d_ws;
    size_t off = 0;
    auto alloc = [&](size_t bytes) -> char* {
        char* p = ws + off;
        off += (bytes + 255) & ~(size_t)255;
        return p;
    };
    __hip_bfloat16* featbf = (__hip_bfloat16*)alloc(16384ull * 2176 * 2);
    __hip_bfloat16* WeTt   = (__hip_bfloat16*)alloc(1024ull * 2176 * 2);
    __hip_bfloat16* WeTb   = (__hip_bfloat16*)alloc(1024ull * 2176 * 2);
    __hip_bfloat16* W1aT   = (__hip_bfloat16*)alloc(1024ull * 1024 * 2);
    __hip_bfloat16* W1bT   = (__hip_bfloat16*)alloc(512ull * 1024 * 2);
    __hip_bfloat16* W2aT   = (__hip_bfloat16*)alloc(512ull * 512 * 2);
    __hip_bfloat16* W2bT   = (__hip_bfloat16*)alloc(512ull * 512 * 2);
    float* eanchor_part    = (float*)alloc(8ull * 512 * 1024 * 4);
    float* eanchor         = (float*)alloc(512ull * 1024 * 4);
    char* bufA             = alloc(16384ull * 1024 * 2);
    char* bufB             = alloc(16384ull * 1024 * 2);
    __hip_bfloat16* h1b    = (__hip_bfloat16*)alloc(16384ull * 512 * 2);

    __hip_bfloat16* act1   = (__hip_bfloat16*)bufA;
    __hip_bfloat16* act2   = (__hip_bfloat16*)bufB;
    __hip_bfloat16* act3   = (__hip_bfloat16*)bufA;
    __hip_bfloat16* act4   = (__hip_bfloat16*)bufB;
    __hip_bfloat16* hsum_b = (__hip_bfloat16*)bufA;

    // ---- fused pre-pass ----
    prepass<<<17408 + 6400, 256, 0, stream>>>(
        features, featbf, We, WeTt, WeTb, W1a, W1aT, W1b, W1bT, W2a, W2aT, W2b, W2bT);

    // ---- anchor GEMM (split-K=8) ----
    gemmk<256, 0, 0><<<dim3(8, 8), 512, 0, stream>>>(
        featbf, 32 * 2176, WeTb, nullptr, nullptr, nullptr,
        nullptr, nullptr, eanchor_part, 512, 1024, 2176, 4);
    anchor_reduce<<<2048, 256, 0, stream>>>(eanchor_part, be, eanchor);

    // ---- L1: act1 = bf16(leaky(feat @ We_top + eanchor_bcast)) ----
    gemmk<256, 2, 1><<<dim3(256), 512, 0, stream>>>(
        featbf, 2176, WeTt, nullptr, nullptr, eanchor,
        act1, nullptr, nullptr, 16384, 1024, 2176, 4);

    // ---- L2: act2 = bf16(leaky(act1 @ W1a + b1a)) ----
    gemmk<256, 0, 1><<<dim3(256), 512, 0, stream>>>(
        act1, 1024, W1aT, b1a, nullptr, nullptr,
        act2, nullptr, nullptr, 16384, 1024, 1024, 4);

    // ---- L3: h1b = bf16(act2 @ W1b + b1b), act3 = bf16(leaky(h1b)) ----
    gemmk<128, 0, 3><<<dim3(256), 512, 0, stream>>>(
        act2, 1024, W1bT, b1b, nullptr, nullptr,
        act3, h1b, nullptr, 16384, 512, 1024, 4);

    // ---- L4: act4 = bf16(leaky(act3 @ W2a + b2a)) ----
    gemmk<128, 0, 1><<<dim3(256), 512, 0, stream>>>(
        act3, 512, W2aT, b2a, nullptr, nullptr,
        act4, nullptr, nullptr, 16384, 512, 512, 4);

    // ---- L5: hsum = bf16(act4 @ W2b + b2b + h1b) ----
    gemmk<128, 1, 2><<<dim3(256), 512, 0, stream>>>(
        act4, 512, W2bT, b2b, h1b, nullptr,
        hsum_b, nullptr, nullptr, 16384, 512, 512, 4);

    // ---- head ----
    final_head<<<4096, 256, 0, stream>>>(hsum_b, Wd, bd, out);
}

// Round 16
// 221.047 us; speedup vs baseline: 1.0692x; 1.0692x over previous
//
#include <hip/hip_runtime.h>
#include <hip/hip_bf16.h>
#include <stdint.h>

typedef __attribute__((ext_vector_type(4))) float f32x4;
typedef __attribute__((ext_vector_type(8))) short bf16x8;

#define BK 64

__device__ inline void gload_lds16(const void* g, void* l) {
    __builtin_amdgcn_global_load_lds(
        (const __attribute__((address_space(1))) void*)g,
        (__attribute__((address_space(3))) void*)l, 16, 0, 0);
}

__device__ inline void wg_barrier() {
    asm volatile("s_barrier" ::: "memory");
}
#define SCHED0 __builtin_amdgcn_sched_barrier(0)
#define VMW(n) asm volatile("s_waitcnt vmcnt(" #n ")" ::: "memory")

// bijective XCD swizzle (m204)
__device__ inline int xcd_swizzle(int orig, int nwg) {
    int q = nwg >> 3, r = nwg & 7;
    int xcd = orig & 7, idx = orig >> 3;
    int base = (xcd < r) ? xcd * (q + 1) : r * (q + 1) + (xcd - r) * q;
    return base + idx;
}

__device__ inline float b2f(short s) {
    union { float f; unsigned u; } x; x.u = ((unsigned)(unsigned short)s) << 16; return x.f;
}
__device__ inline short f2bs(float f) {
    __hip_bfloat16 h = __float2bfloat16(f);
    short s; __builtin_memcpy(&s, &h, 2); return s;
}

// Fused pre-pass (R9 shape; NT hints on the feature stream).
__device__ inline void wt_tile(const float* __restrict__ W, __hip_bfloat16* __restrict__ WT,
                               int K, int N, int KP, int tid, int bid) {
    __shared__ float tile[32][33];
    const int ntn = N >> 5;
    const int tk = bid / ntn, tn = bid - tk * ntn;
    const int k0 = tk * 32, n0 = tn * 32;
    const int c = tid & 31, r8 = tid >> 5;
    #pragma unroll
    for (int p = 0; p < 4; p++) {
        int k = k0 + r8 + p * 8;
        tile[r8 + p * 8][c] = (k < K) ? W[(size_t)k * N + n0 + c] : 0.f;
    }
    __syncthreads();
    #pragma unroll
    for (int p = 0; p < 4; p++) {
        int n = n0 + r8 + p * 8;
        WT[(size_t)n * KP + k0 + c] = __float2bfloat16(tile[c][r8 + p * 8]);
    }
}

__global__ __launch_bounds__(256)
void prepass(const float* __restrict__ feat, __hip_bfloat16* __restrict__ featbf,
             const float* __restrict__ We, __hip_bfloat16* __restrict__ WeTt,
             __hip_bfloat16* __restrict__ WeTb,
             const float* __restrict__ W1a, __hip_bfloat16* __restrict__ W1aT,
             const float* __restrict__ W1b, __hip_bfloat16* __restrict__ W1bT,
             const float* __restrict__ W2a, __hip_bfloat16* __restrict__ W2aT,
             const float* __restrict__ W2b, __hip_bfloat16* __restrict__ W2bT)
{
    const int bid = blockIdx.x;
    const int tid = threadIdx.x;
    if (bid < 17408) {
        int i = bid * 256 + tid;
        int r = i / 272, c8 = (i % 272) * 8;
        bf16x8 o;
        if (c8 < 2144) {
            const f32x4* p = (const f32x4*)(feat + (size_t)r * 2144 + c8);
            f32x4 x0 = __builtin_nontemporal_load(p);
            f32x4 x1 = __builtin_nontemporal_load(p + 1);
            o[0] = f2bs(x0[0]); o[1] = f2bs(x0[1]); o[2] = f2bs(x0[2]); o[3] = f2bs(x0[3]);
            o[4] = f2bs(x1[0]); o[5] = f2bs(x1[1]); o[6] = f2bs(x1[2]); o[7] = f2bs(x1[3]);
        } else {
            #pragma unroll
            for (int j = 0; j < 8; j++) o[j] = f2bs(0.f);
        }
        __builtin_nontemporal_store(o, (bf16x8*)&featbf[(size_t)r * 2176 + c8]);
        return;
    }
    int b = bid - 17408;
    if      (b < 2176) wt_tile(We,                WeTt, 2144, 1024, 2176, tid, b);
    else if (b < 4352) wt_tile(We + 2144 * 1024,  WeTb, 2144, 1024, 2176, tid, b - 2176);
    else if (b < 5376) wt_tile(W1a, W1aT, 1024, 1024, 1024, tid, b - 4352);
    else if (b < 5888) wt_tile(W1b, W1bT, 1024,  512, 1024, tid, b - 5376);
    else if (b < 6144) wt_tile(W2a, W2aT,  512,  512,  512, tid, b - 5888);
    else               wt_tile(W2b, W2bT,  512,  512,  512, tid, b - 6144);
}

// Phase-split never-drain GEMM (R9 champion structure).
// RES_MODE: 0 none, 1 bf16 res[M][N], 2 f32 res[row>>5][N]
// OUTK: 0 f32 scalar (split-K partials), 1 bf16 leaky, 2 bf16 raw, 3 both,
//       4 head-fused (NF==2 only): no tensor output; per-block head partials
//          hpart[row][bx][3] = sum_{cols of this block} leaky(vv)*Wd[col][.]
template<int BN_, int RES_MODE, int OUTK>
__global__ __launch_bounds__(512, 2)
void gemmk(const __hip_bfloat16* __restrict__ A, int lda,
           const __hip_bfloat16* __restrict__ Bt,
           const float* __restrict__ bias,
           const __hip_bfloat16* __restrict__ resb,
           const float* __restrict__ resf,
           __hip_bfloat16* __restrict__ outb,
           __hip_bfloat16* __restrict__ outb2,
           float* __restrict__ outf,
           const float* __restrict__ Wd,
           float* __restrict__ hpart,
           int M, int N, int K, int gx)
{
    constexpr int NF  = BN_ / 64;           // 4 or 2
    constexpr int REL = NF * 16;            // per-wave col span
    __shared__ __hip_bfloat16 lds[2][(256 + BN_) * BK];

    const int nwg  = gridDim.x;
    const int wgid = xcd_swizzle(blockIdx.x, nwg);
    const int by   = wgid / gx;
    const int bx   = wgid - by * gx;

    const int t    = threadIdx.x;
    const int lane = t & 63;
    const int wv   = t >> 6;
    const int wr   = wv >> 2;               // 0..1 (128-row half)
    const int wc   = wv & 3;                // 0..3 (REL-wide col strip)

    const int row0 = by * 256;
    const int col0 = bx * BN_;

    const int NT = K / BK;
    const int split = blockIdx.y;
    const int kb = (split * NT) / gridDim.y;
    const int ke = ((split + 1) * NT) / gridDim.y;
    float* outfs = outf;
    if (OUTK == 0 && gridDim.y > 1) outfs = outf + (size_t)split * M * N;

    const int srow = t >> 3;                                 // 0..63
    const int sc8  = (t & 7) * 8;
    const int scol = sc8 ^ ((srow & 7) << 3);                // inverse-swz src col
    const int sdst = sc8;                                    // linear LDS dest

    f32x4 acc[8][NF];
    #pragma unroll
    for (int i = 0; i < 8; i++)
        #pragma unroll
        for (int j = 0; j < NF; j++)
            acc[i][j] = f32x4{0.f, 0.f, 0.f, 0.f};

    const int lrow = lane & 15;
    const int lk   = (lane >> 4) * 8;
    const int rxor = (lrow & 7) << 3;

    auto stA = [&](int buf, int k0, int b) {
        gload_lds16(A + (size_t)(row0 + b * 64 + srow) * lda + k0 + scol,
                    &lds[buf][(b * 64 + srow) * BK + sdst]);
    };
    auto stB = [&](int buf, int k0, int b) {
        gload_lds16(Bt + (size_t)(col0 + b * 64 + srow) * K + k0 + scol,
                    &lds[buf][(256 + b * 64 + srow) * BK + sdst]);
    };

    bf16x8 af[4][2];
    auto rdA = [&](int buf, int ih) {
        #pragma unroll
        for (int i = 0; i < 4; ++i)
            #pragma unroll
            for (int h = 0; h < 2; ++h)
                af[i][h] = *(const bf16x8*)
                    &lds[buf][(wr * 128 + (ih * 4 + i) * 16 + lrow) * BK + ((h * 32 + lk) ^ rxor)];
    };
    bf16x8 bgl[2][2], bgh[2][2];
    auto rdB2 = [&](int buf, int jb, bf16x8 (&bg)[2][2]) {
        #pragma unroll
        for (int j = 0; j < 2; ++j)
            #pragma unroll
            for (int h = 0; h < 2; ++h)
                bg[j][h] = *(const bf16x8*)
                    &lds[buf][(256 + wc * REL + (jb + j) * 16 + lrow) * BK + ((h * 32 + lk) ^ rxor)];
    };

#define MFMA_Q(BG, IB, JB)                                                    \
    do {                                                                      \
        __builtin_amdgcn_s_setprio(1);                                        \
        _Pragma("unroll") for (int h_ = 0; h_ < 2; ++h_)                      \
        _Pragma("unroll") for (int i_ = 0; i_ < 4; ++i_)                      \
        _Pragma("unroll") for (int j_ = 0; j_ < 2; ++j_)                      \
            acc[(IB) + i_][(JB) + j_] = __builtin_amdgcn_mfma_f32_16x16x32_bf16( \
                af[i_][h_], BG[j_][h_], acc[(IB) + i_][(JB) + j_], 0, 0, 0);  \
        __builtin_amdgcn_s_setprio(0);                                        \
    } while (0)

    // ---- prologue (order defines the vmcnt ledger!) ----
    {
        const int k0 = kb * BK, k1 = (kb + 1) * BK;
        if constexpr (NF == 4) {
            stA(0, k0, 0); stA(0, k0, 2); stA(0, k0, 1); stA(0, k0, 3);
            stB(0, k0, 0); stB(0, k0, 1); stB(0, k0, 2); stB(0, k0, 3);
            stA(1, k1, 0); stA(1, k1, 2); stA(1, k1, 1); stA(1, k1, 3);
        } else {
            stA(0, k0, 0); stA(0, k0, 2); stB(0, k0, 0); stB(0, k0, 1);
            stA(0, k0, 1); stA(0, k0, 3);
            stA(1, k1, 0); stA(1, k1, 2); stB(1, k1, 0); stB(1, k1, 1);
        }
    }

    int cur = 0;
    for (int kt = kb; kt < ke; ++kt) {
        const bool pf1 = (kt + 1 < ke), pf2 = (kt + 2 < ke);
        const int nk1 = (kt + 1) * BK, nk2 = (kt + 2) * BK;
        const int nxt = cur ^ 1;
        if constexpr (NF == 4) {
            // ph0
            if (kt == ke - 1) VMW(0); else VMW(4);
            wg_barrier();
            rdA(cur, 0); rdB2(cur, 0, bgl);
            if (pf1) { stB(nxt, nk1, 0); stB(nxt, nk1, 1); }
            SCHED0;
            MFMA_Q(bgl, 0, 0);
            // ph1
            wg_barrier();
            rdB2(cur, 2, bgh);
            if (pf1) { stB(nxt, nk1, 2); stB(nxt, nk1, 3); }
            SCHED0;
            MFMA_Q(bgh, 0, 2);
            // ph2
            wg_barrier();
            rdA(cur, 1);
            if (pf2) { stA(cur, nk2, 0); stA(cur, nk2, 2); }
            SCHED0;
            MFMA_Q(bgl, 4, 0);
            // ph3
            wg_barrier();
            if (pf2) { stA(cur, nk2, 1); stA(cur, nk2, 3); }
            SCHED0;
            MFMA_Q(bgh, 4, 2);
        } else {
            // ph0
            if (kt == ke - 1) VMW(2); else VMW(6);
            wg_barrier();
            rdA(cur, 0); rdB2(cur, 0, bgl);
            if (pf1) { stA(nxt, nk1, 1); stA(nxt, nk1, 3); }
            SCHED0;
            MFMA_Q(bgl, 0, 0);
            // ph1
            if (kt == ke - 1) VMW(0); else VMW(6);
            wg_barrier();
            rdA(cur, 1);
            if (pf2) { stA(cur, nk2, 0); stA(cur, nk2, 2); stB(cur, nk2, 0); stB(cur, nk2, 1); }
            SCHED0;
            MFMA_Q(bgl, 4, 0);
        }
        cur ^= 1;
    }
#undef MFMA_Q

    // ---- epilogue ----
    if constexpr (OUTK == 0) {
        #pragma unroll
        for (int j = 0; j < NF; j++) {
            const int col = col0 + wc * REL + j * 16 + lrow;
            #pragma unroll
            for (int i = 0; i < 8; i++) {
                const int rbase = row0 + wr * 128 + i * 16 + (lane >> 4) * 4;
                #pragma unroll
                for (int r = 0; r < 4; r++)
                    outfs[(size_t)(rbase + r) * N + col] = acc[i][j][r];
            }
        }
    } else {
        wg_barrier();                       // all LDS reads/loads retired
        __hip_bfloat16* eb = &lds[0][0] + wv * (128 * REL);
        // head-partial scratch BEYOND all eb regions (8 waves x 128*REL elems).
        // NF==2: eb spans [0, 64KB); sp at 64KB; 64+12=76KB < 96KB allocated.
        float* sp = (float*)(&lds[0][0] + 8 * 128 * REL);
        #pragma unroll
        for (int i = 0; i < 8; i++)
            #pragma unroll
            for (int j = 0; j < NF; j++)
                #pragma unroll
                for (int r = 0; r < 4; r++)
                    eb[(i * 16 + (lane >> 4) * 4 + r) * REL + j * 16 + lrow] =
                        __float2bfloat16(acc[i][j][r]);
        constexpr int LPR = REL / 8;
        constexpr int RPI = 64 / LPR;
        constexpr int NIT = 128 / RPI;
        const int lrr = lane / LPR;
        const int lcc = (lane % LPR) * 8;
        const int col = col0 + wc * REL + lcc;
        float bvv[8];
        if (bias) {
            float4 b0 = *(const float4*)&bias[col];
            float4 b1 = *(const float4*)&bias[col + 4];
            bvv[0] = b0.x; bvv[1] = b0.y; bvv[2] = b0.z; bvv[3] = b0.w;
            bvv[4] = b1.x; bvv[5] = b1.y; bvv[6] = b1.z; bvv[7] = b1.w;
        } else {
            #pragma unroll
            for (int e = 0; e < 8; e++) bvv[e] = 0.f;
        }
        #pragma unroll
        for (int it = 0; it < NIT; it++) {
            const int rl  = it * RPI + lrr;
            const int row = row0 + wr * 128 + rl;
            bf16x8 v8 = *(bf16x8*)&eb[rl * REL + lcc];
            float vv[8];
            #pragma unroll
            for (int e = 0; e < 8; e++) vv[e] = b2f(v8[e]) + bvv[e];
            if constexpr (RES_MODE == 1) {
                bf16x8 r8 = *(const bf16x8*)&resb[(size_t)row * N + col];
                #pragma unroll
                for (int e = 0; e < 8; e++) vv[e] += b2f(r8[e]);
            }
            if constexpr (RES_MODE == 2) {
                const float* rp = &resf[(size_t)(row >> 5) * N + col];
                float4 r0 = *(const float4*)rp;
                float4 r1 = *(const float4*)(rp + 4);
                vv[0] += r0.x; vv[1] += r0.y; vv[2] += r0.z; vv[3] += r0.w;
                vv[4] += r1.x; vv[5] += r1.y; vv[6] += r1.z; vv[7] += r1.w;
            }
            if constexpr (OUTK == 4) {
                float t0 = 0.f, t1 = 0.f, t2 = 0.f;
                #pragma unroll
                for (int e = 0; e < 8; e++) {
                    float lv = vv[e] >= 0.f ? vv[e] : 0.01f * vv[e];
                    const float* wd = &Wd[(size_t)(col + e) * 3];
                    t0 += lv * wd[0]; t1 += lv * wd[1]; t2 += lv * wd[2];
                }
                t0 += __shfl_xor(t0, 1); t0 += __shfl_xor(t0, 2);
                t1 += __shfl_xor(t1, 1); t1 += __shfl_xor(t1, 2);
                t2 += __shfl_xor(t2, 1); t2 += __shfl_xor(t2, 2);
                if ((lane & 3) == 0) {
                    float* q = &sp[(size_t)(wr * 128 + rl) * 12 + wc * 3];
                    q[0] = t0; q[1] = t1; q[2] = t2;
                }
            } else {
                bf16x8 o1, o2;
                #pragma unroll
                for (int e = 0; e < 8; e++) {
                    float lv = vv[e] >= 0.f ? vv[e] : 0.01f * vv[e];
                    if constexpr (OUTK == 1) o1[e] = f2bs(lv);
                    if constexpr (OUTK == 2) o1[e] = f2bs(vv[e]);
                    if constexpr (OUTK == 3) { o1[e] = f2bs(lv); o2[e] = f2bs(vv[e]); }
                }
                *(bf16x8*)&outb[(size_t)row * N + col] = o1;
                if constexpr (OUTK == 3)
                    *(bf16x8*)&outb2[(size_t)row * N + col] = o2;
            }
        }
        if constexpr (OUTK == 4) {
            wg_barrier();
            if (t < 256) {
                const float* q = &sp[(size_t)t * 12];
                float a0 = q[0] + q[3] + q[6] + q[9];
                float a1 = q[1] + q[4] + q[7] + q[10];
                float a2 = q[2] + q[5] + q[8] + q[11];
                float* hp = &hpart[(size_t)(row0 + t) * 12 + bx * 3];
                hp[0] = a0; hp[1] = a1; hp[2] = a2;
            }
        }
    }
}

// eanchor = sum of 8 split-K partials + be
__global__ __launch_bounds__(256)
void anchor_reduce(const float* __restrict__ part, const float* __restrict__ be,
                   float* __restrict__ out) {
    int i = blockIdx.x * 256 + threadIdx.x;
    if (i >= 512 * 1024) return;
    const int S = 512 * 1024;
    int col = i & 1023;
    float s = be[col];
    #pragma unroll
    for (int p = 0; p < 8; p++) s += part[i + p * S];
    out[i] = s;
}

// out[row][c] = sum_bx hpart[row][bx][c] + bd[c] + (c==2)
__global__ __launch_bounds__(256)
void head_reduce(const float* __restrict__ hpart, const float* __restrict__ bd,
                 float* __restrict__ out)
{
    int row = blockIdx.x * 256 + threadIdx.x;
    if (row >= 16384) return;
    const float* p = hpart + (size_t)row * 12;
    out[row * 3 + 0] = p[0] + p[3] + p[6] + p[9]  + bd[0];
    out[row * 3 + 1] = p[1] + p[4] + p[7] + p[10] + bd[1];
    out[row * 3 + 2] = p[2] + p[5] + p[8] + p[11] + bd[2] + 1.0f;
}

extern "C" void kernel_launch(void* const* d_in, const int* in_sizes, int n_in,
                              void* d_out, int out_size, void* d_ws, size_t ws_size,
                              hipStream_t stream)
{
    const float* features = (const float*)d_in[0];
    const float* We  = (const float*)d_in[1];
    const float* be  = (const float*)d_in[2];
    const float* W1a = (const float*)d_in[3];
    const float* b1a = (const float*)d_in[4];
    const float* W1b = (const float*)d_in[5];
    const float* b1b = (const float*)d_in[6];
    const float* W2a = (const float*)d_in[7];
    const float* b2a = (const float*)d_in[8];
    const float* W2b = (const float*)d_in[9];
    const float* b2b = (const float*)d_in[10];
    const float* Wd  = (const float*)d_in[11];
    const float* bd  = (const float*)d_in[12];
    float* out = (float*)d_out;

    char* ws = (char*)d_ws;
    size_t off = 0;
    auto alloc = [&](size_t bytes) -> char* {
        char* p = ws + off;
        off += (bytes + 255) & ~(size_t)255;
        return p;
    };
    __hip_bfloat16* featbf = (__hip_bfloat16*)alloc(16384ull * 2176 * 2);
    __hip_bfloat16* WeTt   = (__hip_bfloat16*)alloc(1024ull * 2176 * 2);
    __hip_bfloat16* WeTb   = (__hip_bfloat16*)alloc(1024ull * 2176 * 2);
    __hip_bfloat16* W1aT   = (__hip_bfloat16*)alloc(1024ull * 1024 * 2);
    __hip_bfloat16* W1bT   = (__hip_bfloat16*)alloc(512ull * 1024 * 2);
    __hip_bfloat16* W2aT   = (__hip_bfloat16*)alloc(512ull * 512 * 2);
    __hip_bfloat16* W2bT   = (__hip_bfloat16*)alloc(512ull * 512 * 2);
    float* eanchor_part    = (float*)alloc(8ull * 512 * 1024 * 4);
    float* eanchor         = (float*)alloc(512ull * 1024 * 4);
    char* bufA             = alloc(16384ull * 1024 * 2);
    char* bufB             = alloc(16384ull * 1024 * 2);
    __hip_bfloat16* h1b    = (__hip_bfloat16*)alloc(16384ull * 512 * 2);
    float* hpart           = (float*)alloc(16384ull * 12 * 4);

    __hip_bfloat16* act1   = (__hip_bfloat16*)bufA;
    __hip_bfloat16* act2   = (__hip_bfloat16*)bufB;
    __hip_bfloat16* act3   = (__hip_bfloat16*)bufA;
    __hip_bfloat16* act4   = (__hip_bfloat16*)bufB;

    // ---- fused pre-pass (NT feature stream) ----
    prepass<<<17408 + 6400, 256, 0, stream>>>(
        features, featbf, We, WeTt, WeTb, W1a, W1aT, W1b, W1bT, W2a, W2aT, W2b, W2bT);

    // ---- anchor GEMM (split-K=8) ----
    gemmk<256, 0, 0><<<dim3(8, 8), 512, 0, stream>>>(
        featbf, 32 * 2176, WeTb, nullptr, nullptr, nullptr,
        nullptr, nullptr, eanchor_part, nullptr, nullptr, 512, 1024, 2176, 4);
    anchor_reduce<<<2048, 256, 0, stream>>>(eanchor_part, be, eanchor);

    // ---- L1: act1 = bf16(leaky(feat @ We_top + eanchor_bcast)) ----
    gemmk<256, 2, 1><<<dim3(256), 512, 0, stream>>>(
        featbf, 2176, WeTt, nullptr, nullptr, eanchor,
        act1, nullptr, nullptr, nullptr, nullptr, 16384, 1024, 2176, 4);

    // ---- L2: act2 = bf16(leaky(act1 @ W1a + b1a)) ----
    gemmk<256, 0, 1><<<dim3(256), 512, 0, stream>>>(
        act1, 1024, W1aT, b1a, nullptr, nullptr,
        act2, nullptr, nullptr, nullptr, nullptr, 16384, 1024, 1024, 4);

    // ---- L3: h1b = bf16(act2 @ W1b + b1b), act3 = bf16(leaky(h1b)) ----
    gemmk<128, 0, 3><<<dim3(256), 512, 0, stream>>>(
        act2, 1024, W1bT, b1b, nullptr, nullptr,
        act3, h1b, nullptr, nullptr, nullptr, 16384, 512, 1024, 4);

    // ---- L4: act4 = bf16(leaky(act3 @ W2a + b2a)) ----
    gemmk<128, 0, 1><<<dim3(256), 512, 0, stream>>>(
        act3, 512, W2aT, b2a, nullptr, nullptr,
        act4, nullptr, nullptr, nullptr, nullptr, 16384, 512, 512, 4);

    // ---- L5 + head (fused) ----
    gemmk<128, 1, 4><<<dim3(256), 512, 0, stream>>>(
        act4, 512, W2bT, b2b, h1b, nullptr,
        nullptr, nullptr, nullptr, Wd, hpart, 16384, 512, 512, 4);

    // ---- head reduce ----
    head_reduce<<<64, 256, 0, stream>>>(hpart, bd, out);
}